// Round 6
// baseline (91.513 us; speedup 1.0000x reference)
//
#include <hip/hip_runtime.h>
#include <math.h>

#define C_FINE   100
#define C_MID    20
#define C_COARSE 5
#define D        128
#define NROWS    262144
#define NPAIRS   4950   // 100*99/2
#define NBLK4    78     // ceil(4950/64)

#define WPG      768            // kAcc blocks (1 wave each; 51.6KB LDS -> 3/CU)
#define BATCH    16             // rows per batch (8 KB in flight per wave)
#define NBATCH   (NROWS/BATCH)  // 16384 (exact)
#define RG       8              // kRed split per class
#define RB       (WPG/RG)       // 96 partials per reduce block
#define PSTR     12928          // partial stride floats (12800 sums + 100 cnt + pad)

// ws layout in floats
#define FP_OFF    0        // fine protos [100][128]
#define DM_OFF    12800    // mid dist table [20][20]
#define DC_OFF    13200    // coarse dist table [5][5]
#define ACC_OFF   13232    // 5 doubles (byte 52928, 8-aligned)
#define DONE_OFF  13244    // int completion counter
#define CNT_OFF   13248    // class counts [100] (float)
#define FSUM_OFF  13360    // fine sums [100][128]
#define PART_OFF  26176    // partials: WPG x PSTR

// ---------------- kAcc: streaming segment-sum, wave-private LDS, no atomics ----------------
__global__ __launch_bounds__(64) void kAcc(const float* __restrict__ rep,
                                           const int* __restrict__ tgt,
                                           float* __restrict__ ws) {
    __shared__ float acc[C_FINE][D];   // 51.2 KB, private to this 1-wave block
    __shared__ float cnt[C_FINE];
    const int lane = threadIdx.x;
    const int wid  = blockIdx.x;

    for (int e = lane; e < C_FINE * D / 4; e += 64)
        ((float4*)acc)[e] = make_float4(0.f, 0.f, 0.f, 0.f);
    for (int e = lane; e < C_FINE; e += 64) cnt[e] = 0.f;
    if (wid == 0) {   // zero FSUM+CNT region for kRed's atomic merge (3228 float4s)
        for (int e = lane; e < 3228; e += 64)
            ((float4*)(ws + CNT_OFF))[e] = make_float4(0.f, 0.f, 0.f, 0.f);
    }
    __syncthreads();

    const float4* rep4 = (const float4*)rep;
    const int2*   tgt2 = (const int2*)tgt;

    for (int b = wid; b < NBATCH; b += WPG) {
        const int base = b * BATCH;
        float4 v[8]; int2 cc[8];
        #pragma unroll
        for (int u = 0; u < 8; ++u)            // 8 x 1KB contiguous loads in flight
            v[u] = rep4[(size_t)(base + 2 * u) * 32 + lane];
        #pragma unroll
        for (int u = 0; u < 8; ++u)
            cc[u] = tgt2[base / 2 + u];
        #pragma unroll
        for (int u = 0; u < 8; ++u) {
            const int cA = cc[u].x, cB = cc[u].y;   // wave-uniform
            if (cA == cB) {
                // both rows same class: combine halves, lower half writes once
                float4 w;
                w.x = __shfl(v[u].x, lane | 32);
                w.y = __shfl(v[u].y, lane | 32);
                w.z = __shfl(v[u].z, lane | 32);
                w.w = __shfl(v[u].w, lane | 32);
                if (lane < 32) {
                    float4 a = *(float4*)&acc[cA][lane * 4];
                    a.x += v[u].x + w.x; a.y += v[u].y + w.y;
                    a.z += v[u].z + w.z; a.w += v[u].w + w.w;
                    *(float4*)&acc[cA][lane * 4] = a;
                    if (lane == 0) cnt[cA] += 2.f;
                }
            } else {
                const int myc = (lane < 32) ? cA : cB;
                const int dl  = (lane & 31) * 4;
                float4 a = *(float4*)&acc[myc][dl];
                a.x += v[u].x; a.y += v[u].y; a.z += v[u].z; a.w += v[u].w;
                *(float4*)&acc[myc][dl] = a;
                if ((lane & 31) == 0) cnt[myc] += 1.f;
            }
        }
    }
    __syncthreads();

    float* part = ws + PART_OFF + (size_t)wid * PSTR;
    for (int e = lane; e < C_FINE * D / 4; e += 64)
        ((float4*)part)[e] = ((const float4*)acc)[e];
    for (int e = lane; e < C_FINE; e += 64) part[12800 + e] = cnt[e];
}

// ---------------- kRed: merge 768 partials -> FSUM + CNT (atomic, L3-hot) ----------------
__global__ __launch_bounds__(128) void kRed(float* __restrict__ ws) {
    const int c = blockIdx.x >> 3, g = blockIdx.x & 7;
    const int t = threadIdx.x;
    const float* p = ws + PART_OFF + (size_t)(g * RB) * PSTR + c * D + t;
    float s = 0.f;
    #pragma unroll 8
    for (int b = 0; b < RB; ++b) s += p[(size_t)b * PSTR];
    atomicAdd(ws + FSUM_OFF + c * D + t, s);

    float cl = (t < RB) ? ws[PART_OFF + (size_t)(g * RB + t) * PSTR + 12800 + c] : 0.f;
    for (int off = 32; off > 0; off >>= 1) cl += __shfl_down(cl, off);
    __shared__ float r2[2];
    if ((t & 63) == 0) r2[t >> 6] = cl;
    __syncthreads();
    if (t == 0) atomicAdd(ws + CNT_OFF + c, r2[0] + r2[1]);
}

// ---------------- k3: normalize + hierarchy + distance tables (all in LDS) ----------------
__global__ __launch_bounds__(256) void k3_hier(const int* __restrict__ f2m,
                                               const int* __restrict__ f2c,
                                               float* __restrict__ ws) {
    __shared__ float fineP[C_FINE][D];        // 51.2 KB
    __shared__ float midP[C_MID][D + 1];
    __shared__ float coarP[C_COARSE][D + 1];
    __shared__ int   sf2m[C_FINE], sf2c[C_FINE], m2c[C_MID];
    __shared__ float midCnt[C_MID], coarCnt[C_COARSE];
    __shared__ float sTot[C_FINE];
    const int t = threadIdx.x;

    if (t < C_FINE) {
        sf2m[t] = f2m[t]; sf2c[t] = f2c[t];
        sTot[t] = ws[CNT_OFF + t];
    }
    for (int e = t; e < C_MID * (D + 1); e += 256) ((float*)midP)[e] = 0.f;
    for (int e = t; e < C_COARSE * (D + 1); e += 256) ((float*)coarP)[e] = 0.f;
    __syncthreads();

    // normalize fine sums -> fineP (LDS + global for k45)
    for (int e = t; e < C_FINE * D; e += 256) {
        int c = e >> 7, d = e & 127;
        float v = ws[FSUM_OFF + e] / fmaxf(sTot[c], 1.f);
        fineP[c][d] = v;
        ws[FP_OFF + e] = v;
    }
    if (t < C_MID) {
        int cntv = 0, mx = -2147483647;
        for (int f = 0; f < C_FINE; ++f)
            if (sf2m[f] == t) { ++cntv; mx = max(mx, sf2c[f]); }
        midCnt[t] = (float)max(cntv, 1);
        m2c[t] = mx;
    }
    __syncthreads();

    if (t < D) {
        const int d = t;
        for (int f = 0; f < C_FINE; ++f)
            midP[sf2m[f]][d] += fineP[f][d];
        for (int m = 0; m < C_MID; ++m)
            midP[m][d] /= midCnt[m];
    }
    if (t >= 128 && t < 128 + C_COARSE) {
        int cc = t - 128, cntv = 0;
        for (int m = 0; m < C_MID; ++m) if (m2c[m] == cc) ++cntv;
        coarCnt[cc] = (float)max(cntv, 1);
    }
    __syncthreads();

    if (t < D) {
        const int d = t;
        for (int m = 0; m < C_MID; ++m)
            coarP[m2c[m]][d] += midP[m][d];
        for (int cc = 0; cc < C_COARSE; ++cc)
            coarP[cc][d] /= coarCnt[cc];
    }
    __syncthreads();

    for (int e = t; e < C_MID * C_MID; e += 256) {
        int m1 = e / C_MID, m2 = e % C_MID;
        float ss = 0.f;
        #pragma unroll 8
        for (int d = 0; d < D; ++d) {
            float df = midP[m1][d] - midP[m2][d];
            ss += df * df;
        }
        ws[DM_OFF + e] = sqrtf(ss + 1e-12f);
    }
    for (int e = t; e < C_COARSE * C_COARSE; e += 256) {
        int c1 = e / C_COARSE, c2 = e % C_COARSE;
        float ss = 0.f;
        #pragma unroll 8
        for (int d = 0; d < D; ++d) {
            float df = coarP[c1][d] - coarP[c2][d];
            ss += df * df;
        }
        ws[DC_OFF + e] = sqrtf(ss + 1e-12f);
    }
    if (t < 5) ((double*)(ws + ACC_OFF))[t] = 0.0;   // zero moment accumulators
    if (t == 5) ((int*)ws + DONE_OFF)[0] = 0;        // zero completion counter
}

// ---------------- k45: all fine pairs -> moments, last block finalizes ----------------
__global__ __launch_bounds__(64) void k45_pairs(float* __restrict__ ws,
                                                const int* __restrict__ f2m,
                                                const int* __restrict__ f2c,
                                                float* __restrict__ out) {
    const int p = blockIdx.x * 64 + threadIdx.x;
    double st = 0, sp = 0, stp = 0, stt = 0, spp = 0;
    if (p < NPAIRS) {
        int i = 0, rem = p;
        while (rem >= C_FINE - 1 - i) { rem -= C_FINE - 1 - i; ++i; }
        int j = i + 1 + rem;

        const float4* Fi = (const float4*)(ws + FP_OFF + i * D);
        const float4* Fj = (const float4*)(ws + FP_OFF + j * D);
        float ss = 0.f;
        #pragma unroll
        for (int k = 0; k < D / 4; ++k) {
            float4 a = Fi[k], b = Fj[k];
            float dx = a.x - b.x, dy = a.y - b.y, dz = a.z - b.z, dw = a.w - b.w;
            ss += dx * dx + dy * dy + dz * dz + dw * dw;
        }
        float proto = sqrtf(ss + 1e-12f);
        float tree  = ws[DC_OFF + f2c[i] * C_COARSE + f2c[j]]
                    + ws[DM_OFF + f2m[i] * C_MID + f2m[j]];
        st = tree; sp = proto;
        stp = (double)tree * (double)proto;
        stt = (double)tree * (double)tree;
        spp = (double)proto * (double)proto;
    }
    for (int off = 32; off > 0; off >>= 1) {
        st  += __shfl_down(st, off);
        sp  += __shfl_down(sp, off);
        stp += __shfl_down(stp, off);
        stt += __shfl_down(stt, off);
        spp += __shfl_down(spp, off);
    }
    if (threadIdx.x == 0) {
        double* acc = (double*)(ws + ACC_OFF);
        atomicAdd(&acc[0], st);
        atomicAdd(&acc[1], sp);
        atomicAdd(&acc[2], stp);
        atomicAdd(&acc[3], stt);
        atomicAdd(&acc[4], spp);
        __threadfence();
        int* done = (int*)ws + DONE_OFF;
        int ticket = atomicAdd(done, 1);
        if (ticket == NBLK4 - 1) {
            double fst  = atomicAdd(&acc[0], 0.0);
            double fsp  = atomicAdd(&acc[1], 0.0);
            double fstp = atomicAdd(&acc[2], 0.0);
            double fstt = atomicAdd(&acc[3], 0.0);
            double fspp = atomicAdd(&acc[4], 0.0);
            const double n = (double)NPAIRS;
            double num = fstp - fst * fsp / n;
            double dtt = fstt - fst * fst / n;
            double dpp = fspp - fsp * fsp / n;
            double corr = num / sqrt(dtt * dpp + 1e-12);
            out[0] = (float)(1.0 - corr);
        }
    }
}

extern "C" void kernel_launch(void* const* d_in, const int* in_sizes, int n_in,
                              void* d_out, int out_size, void* d_ws, size_t ws_size,
                              hipStream_t stream) {
    const float* rep = (const float*)d_in[0];
    const int*   tgt = (const int*)d_in[1];
    const int*   f2m = (const int*)d_in[2];
    const int*   f2c = (const int*)d_in[3];
    float* ws  = (float*)d_ws;
    float* out = (float*)d_out;

    hipLaunchKernelGGL(kAcc,      dim3(WPG),         dim3(64),  0, stream, rep, tgt, ws);
    hipLaunchKernelGGL(kRed,      dim3(C_FINE * RG), dim3(128), 0, stream, ws);
    hipLaunchKernelGGL(k3_hier,   dim3(1),           dim3(256), 0, stream, f2m, f2c, ws);
    hipLaunchKernelGGL(k45_pairs, dim3(NBLK4),       dim3(64),  0, stream,
                       ws, f2m, f2c, out);
}